// Round 12
// baseline (219.101 us; speedup 1.0000x reference)
//
#include <hip/hip_runtime.h>
#include <math.h>

constexpr int Lq = 8, Cq = 16, Hq = 240, Wq = 480, MIDq = 8, SEM = 4;
constexpr int HWq = Hq * Wq;

__device__ __forceinline__ float sigmoidf_(float v) { return 1.0f / (1.0f + expf(-v)); }

// conv1: x (L,16,H,W) -> silu -> f1 (L,8,H,W), 3x3 SAME zero-pad.
// R12: per halo-row, batch-load float4 mid[16] (16 loads in flight) BEFORE
// any FMA -> breaks the 1-deep load->wait->FMA serialization that pinned
// conv1 at ~59us across R5/R6/R10/R11. Halo via __shfl of neighbor mids.
__global__ void k_conv1(const float* __restrict__ x, const float* __restrict__ w1,
                        const float* __restrict__ b1, float* __restrict__ f1) {
    int b = blockIdx.x;
    int l = b & 7, y = b >> 3;
    int t = threadIdx.x;
    int lane = t & 63;
    int tc = t < 120 ? t : 119;       // dup threads keep shfl sources defined
    int xi = tc * 4;
    float acc[MIDq][4];
#pragma unroll
    for (int m = 0; m < MIDq; m++) {
        float bv = b1[m];
#pragma unroll
        for (int o = 0; o < 4; o++) acc[m][o] = bv;
    }
    const float* xbase = x + (size_t)l * Cq * HWq;
#pragma unroll
    for (int r = 0; r < 3; r++) {
        int yy = y + r - 1;
        if (yy < 0 || yy >= Hq) continue;        // uniform per block
        const float* rowp = xbase + (size_t)yy * Wq;
        float4 mid[Cq];
#pragma unroll
        for (int ic = 0; ic < Cq; ic++)
            mid[ic] = *(const float4*)(rowp + (size_t)ic * HWq + xi);
#pragma unroll
        for (int ic = 0; ic < Cq; ic++) {
            float lft = __shfl_up(mid[ic].w, 1, 64);
            if (lane == 0) lft = (xi == 0) ? 0.f : rowp[(size_t)ic * HWq + xi - 1];
            float rgt = __shfl_down(mid[ic].x, 1, 64);
            if (lane == 63) rgt = (xi + 4 < Wq) ? rowp[(size_t)ic * HWq + xi + 4] : 0.f;
            if (xi + 4 >= Wq) rgt = 0.f;
            float in6[6] = {lft, mid[ic].x, mid[ic].y, mid[ic].z, mid[ic].w, rgt};
#pragma unroll
            for (int m = 0; m < MIDq; m++) {
                const float* wp = w1 + ((size_t)m * Cq + ic) * 9 + r * 3;
                float w0 = wp[0], w1v = wp[1], w2v = wp[2];
#pragma unroll
                for (int o = 0; o < 4; o++)
                    acc[m][o] = fmaf(w0, in6[o],
                                fmaf(w1v, in6[o + 1],
                                fmaf(w2v, in6[o + 2], acc[m][o])));
            }
        }
    }
    if (t < 120) {
        size_t rowoff = (size_t)y * Wq + xi;
#pragma unroll
        for (int m = 0; m < MIDq; m++) {
            float4 v;
            float a0 = acc[m][0], a1 = acc[m][1], a2 = acc[m][2], a3 = acc[m][3];
            v.x = a0 * sigmoidf_(a0);
            v.y = a1 * sigmoidf_(a1);
            v.z = a2 * sigmoidf_(a2);
            v.w = a3 * sigmoidf_(a3);
            *(float4*)(f1 + (size_t)(l * MIDq + m) * HWq + rowoff) = v;
        }
    }
}

// conv2: f1 (L,8,H,W) -> f (L,2,H,W), 3x3 SAME zero-pad. Same batching.
__global__ void k_conv2(const float* __restrict__ f1, const float* __restrict__ w2,
                        const float* __restrict__ b2, float* __restrict__ f) {
    int b = blockIdx.x;
    int l = b & 7, y = b >> 3;
    int t = threadIdx.x;
    int lane = t & 63;
    int tc = t < 120 ? t : 119;
    int xi = tc * 4;
    float acc[2][4];
#pragma unroll
    for (int m = 0; m < 2; m++) {
        float bv = b2[m];
#pragma unroll
        for (int o = 0; o < 4; o++) acc[m][o] = bv;
    }
    const float* fbase = f1 + (size_t)l * MIDq * HWq;
#pragma unroll
    for (int r = 0; r < 3; r++) {
        int yy = y + r - 1;
        if (yy < 0 || yy >= Hq) continue;
        const float* rowp = fbase + (size_t)yy * Wq;
        float4 mid[MIDq];
#pragma unroll
        for (int ic = 0; ic < MIDq; ic++)
            mid[ic] = *(const float4*)(rowp + (size_t)ic * HWq + xi);
#pragma unroll
        for (int ic = 0; ic < MIDq; ic++) {
            float lft = __shfl_up(mid[ic].w, 1, 64);
            if (lane == 0) lft = (xi == 0) ? 0.f : rowp[(size_t)ic * HWq + xi - 1];
            float rgt = __shfl_down(mid[ic].x, 1, 64);
            if (lane == 63) rgt = (xi + 4 < Wq) ? rowp[(size_t)ic * HWq + xi + 4] : 0.f;
            if (xi + 4 >= Wq) rgt = 0.f;
            float in6[6] = {lft, mid[ic].x, mid[ic].y, mid[ic].z, mid[ic].w, rgt};
#pragma unroll
            for (int m = 0; m < 2; m++) {
                const float* wp = w2 + ((size_t)m * MIDq + ic) * 9 + r * 3;
                float w0 = wp[0], w1v = wp[1], w2v = wp[2];
#pragma unroll
                for (int o = 0; o < 4; o++)
                    acc[m][o] = fmaf(w0, in6[o],
                                fmaf(w1v, in6[o + 1],
                                fmaf(w2v, in6[o + 2], acc[m][o])));
            }
        }
    }
    if (t < 120) {
        size_t rowoff = (size_t)y * Wq + xi;
#pragma unroll
        for (int m = 0; m < 2; m++) {
            float4 v = {acc[m][0], acc[m][1], acc[m][2], acc[m][3]};
            *(float4*)(f + (size_t)(l * 2 + m) * HWq + rowoff) = v;
        }
    }
}

// sobel (wrap-x, edge-y) + metric + tanh -> flow (L,2,H,W) (R5 exact)
__global__ void k_flow(const float* __restrict__ f, float* __restrict__ flow) {
    int idx = blockIdx.x * blockDim.x + threadIdx.x;
    if (idx >= Lq * HWq) return;
    int l = idx / HWq, rem = idx % HWq, y = rem / Wq, x = rem % Wq;
    const float* phi = f + (size_t)(l * 2 + 0) * HWq;
    const float* psi = f + (size_t)(l * 2 + 1) * HWq;
    float ph[3][3], ps[3][3];
#pragma unroll
    for (int i = 0; i < 3; i++) {
        int yy = y + i - 1;
        yy = yy < 0 ? 0 : (yy >= Hq ? Hq - 1 : yy);
#pragma unroll
        for (int j = 0; j < 3; j++) {
            int xx = x + j - 1;
            xx = (xx + Wq) % Wq;
            ph[i][j] = phi[yy * Wq + xx];
            ps[i][j] = psi[yy * Wq + xx];
        }
    }
    float gxp = (ph[0][2] - ph[0][0]) + 2.f * (ph[1][2] - ph[1][0]) + (ph[2][2] - ph[2][0]);
    float gyp = (ph[2][0] + 2.f * ph[2][1] + ph[2][2]) - (ph[0][0] + 2.f * ph[0][1] + ph[0][2]);
    float gxs = (ps[0][2] - ps[0][0]) + 2.f * (ps[1][2] - ps[1][0]) + (ps[2][2] - ps[2][0]);
    float gys = (ps[2][0] + 2.f * ps[2][1] + ps[2][2]) - (ps[0][0] + 2.f * ps[0][1] + ps[0][2]);
    float latf = (float)(-M_PI * 0.5 + (double)y * (M_PI / (double)(Hq - 1)));
    float metric = (float)(1.0 / (cos((double)latf) + 1e-6));
    float u = gxp * metric - gys;
    float v = gyp + gxs * metric;
    flow[(size_t)(l * 2 + 0) * HWq + rem] = tanhf(u);
    flow[(size_t)(l * 2 + 1) * HWq + rem] = tanhf(v);
}

// one-time: m0[px][c] = mean_r h0[c][px][r]   (h0: (C,H,W,R) fp32, R=8)
__global__ void k_m0(const float* __restrict__ h0, float* __restrict__ m0) {
    int px = blockIdx.x * 256 + threadIdx.x;
    const float4* h4 = (const float4*)h0;
    float4* mp = (float4*)(m0 + (size_t)px * Cq);
#pragma unroll
    for (int cq = 0; cq < 4; cq++) {
        float vals[4];
#pragma unroll
        for (int cc = 0; cc < 4; cc++) {
            int c = cq * 4 + cc;
            float4 a = h4[(size_t)(c * HWq + px) * 2];
            float4 b = h4[(size_t)(c * HWq + px) * 2 + 1];
            vals[cc] = (a.x + a.y + a.z + a.w + b.x + b.y + b.z + b.w) * 0.125f;
        }
        float4 o = {vals[0], vals[1], vals[2], vals[3]};
        mp[cq] = o;
    }
}

// Fused scan step (R11 form: 2 barriers, SE recomputed in registers).
__global__ __launch_bounds__(1024) void k_step(const float* __restrict__ min_,
                       float* __restrict__ mout, const float* __restrict__ flow_l,
                       const float* __restrict__ xl, const float* __restrict__ listT,
                       int l,
                       const float* __restrict__ sw1, const float* __restrict__ sb1,
                       const float* __restrict__ sw2, const float* __restrict__ sb2,
                       float* __restrict__ out_l) {
    constexpr int STR = 17;                     // LDS row stride (coprime 32)
    __shared__ float sm[Wq * STR];
    __shared__ float csum[Cq];

    int y = blockIdx.x;
    int t = threadIdx.x;
    int wave = t >> 6, lane = t & 63;
    bool act = t < 2 * Wq;
    int px = act ? (t >> 1) : (Wq - 1);
    int half = t & 1;
    int c0 = half * 8;

    float dt = listT[l];
    float mn[8];
    {
        float u = flow_l[y * Wq + px];
        float v = flow_l[HWq + y * Wq + px];
        float gx = (px * (2.0f / (Wq - 1)) - 1.0f) - u * dt;
        float gy = (y * (2.0f / (Hq - 1)) - 1.0f) - v * dt;
        float xp = fminf(fmaxf((gx + 1.0f) * (Wq * 0.5f) - 0.5f, 0.0f), (float)(Wq - 1));
        float yp = fminf(fmaxf((gy + 1.0f) * (Hq * 0.5f) - 0.5f, 0.0f), (float)(Hq - 1));
        float x0f = floorf(xp), y0f = floorf(yp);
        float wx = xp - x0f, wy = yp - y0f;
        int x0 = (int)x0f, y0 = (int)y0f;
        int x1 = min(x0 + 1, Wq - 1), y1 = min(y0 + 1, Hq - 1);
        const float4* m4 = (const float4*)min_;
        size_t b00 = (size_t)(y0 * Wq + x0) * 4 + (half * 2);
        size_t b01 = (size_t)(y0 * Wq + x1) * 4 + (half * 2);
        size_t b10 = (size_t)(y1 * Wq + x0) * 4 + (half * 2);
        size_t b11 = (size_t)(y1 * Wq + x1) * 4 + (half * 2);
        float4 A0 = m4[b00], A1 = m4[b00 + 1];
        float4 B0 = m4[b01], B1 = m4[b01 + 1];
        float4 C0 = m4[b10], C1 = m4[b10 + 1];
        float4 D0 = m4[b11], D1 = m4[b11 + 1];
        float w00 = (1.f - wx) * (1.f - wy), w01 = wx * (1.f - wy);
        float w10 = (1.f - wx) * wy, w11 = wx * wy;
        const float* xb = xl + y * Wq + px;
        float xv[8];
#pragma unroll
        for (int j = 0; j < 8; j++) xv[j] = xb[(size_t)(c0 + j) * HWq];
        mn[0] = w00 * A0.x + w01 * B0.x + w10 * C0.x + w11 * D0.x + xv[0];
        mn[1] = w00 * A0.y + w01 * B0.y + w10 * C0.y + w11 * D0.y + xv[1];
        mn[2] = w00 * A0.z + w01 * B0.z + w10 * C0.z + w11 * D0.z + xv[2];
        mn[3] = w00 * A0.w + w01 * B0.w + w10 * C0.w + w11 * D0.w + xv[3];
        mn[4] = w00 * A1.x + w01 * B1.x + w10 * C1.x + w11 * D1.x + xv[4];
        mn[5] = w00 * A1.y + w01 * B1.y + w10 * C1.y + w11 * D1.y + xv[5];
        mn[6] = w00 * A1.z + w01 * B1.z + w10 * C1.z + w11 * D1.z + xv[6];
        mn[7] = w00 * A1.w + w01 * B1.w + w10 * C1.w + w11 * D1.w + xv[7];
    }
    if (act) {
        float4* mo = (float4*)(mout + (size_t)(y * Wq + px) * Cq + c0);
        float4 o0 = {mn[0], mn[1], mn[2], mn[3]};
        float4 o1 = {mn[4], mn[5], mn[6], mn[7]};
        mo[0] = o0;
        mo[1] = o1;
#pragma unroll
        for (int j = 0; j < 8; j++) sm[px * STR + c0 + j] = mn[j];
    }
    __syncthreads();
    {
        float s = 0.f;
#pragma unroll
        for (int k = 0; k < 8; k++) {
            int p = k * 64 + lane;
            if (p < Wq) s += sm[p * STR + wave];
        }
#pragma unroll
        for (int off = 32; off > 0; off >>= 1) s += __shfl_down(s, off, 64);
        if (lane == 0) csum[wave] = s;
    }
    __syncthreads();
    if (act) {
        float ym[Cq];
#pragma unroll
        for (int i = 0; i < Cq; i++) ym[i] = csum[i] * (1.0f / Wq);
        float z[SEM];
#pragma unroll
        for (int mm = 0; mm < SEM; mm++) {
            float a = sb1[mm];
#pragma unroll
            for (int i = 0; i < Cq; i++) a = fmaf(sw1[mm * Cq + i], ym[i], a);
            z[mm] = a * sigmoidf_(a);
        }
        float* ob = out_l + y * Wq + px;
#pragma unroll
        for (int j = 0; j < 8; j++) {
            float a = sb2[c0 + j];
#pragma unroll
            for (int mm = 0; mm < SEM; mm++) a = fmaf(sw2[(c0 + j) * SEM + mm], z[mm], a);
            ob[(size_t)(c0 + j) * HWq] = mn[j] * sigmoidf_(a);
        }
    }
}

extern "C" void kernel_launch(void* const* d_in, const int* in_sizes, int n_in,
                              void* d_out, int out_size, void* d_ws, size_t ws_size,
                              hipStream_t stream) {
    const float* x = (const float*)d_in[0];
    const float* h0 = (const float*)d_in[1];
    const float* listT = (const float*)d_in[2];
    const float* hw1 = (const float*)d_in[3];
    const float* hb1 = (const float*)d_in[4];
    const float* hw2 = (const float*)d_in[5];
    const float* hb2 = (const float*)d_in[6];
    const float* sw1 = (const float*)d_in[7];
    const float* sb1 = (const float*)d_in[8];
    const float* sw2 = (const float*)d_in[9];
    const float* sb2 = (const float*)d_in[10];
    float* out = (float*)d_out;
    char* ws = (char*)d_ws;

    size_t off = 0;
    float* flow = (float*)(ws + off); off += sizeof(float) * (size_t)Lq * 2 * HWq;
    float* f    = (float*)(ws + off); off += sizeof(float) * (size_t)Lq * 2 * HWq;
    float* f1   = (float*)(ws + off); off += sizeof(float) * (size_t)Lq * MIDq * HWq;
    float* mA   = (float*)(ws + off); off += sizeof(float) * (size_t)HWq * Cq;
    float* mB   = (float*)(ws + off); off += sizeof(float) * (size_t)HWq * Cq;

    k_conv1<<<Lq * Hq, 128, 0, stream>>>(x, hw1, hb1, f1);
    k_conv2<<<Lq * Hq, 128, 0, stream>>>(f1, hw2, hb2, f);
    k_flow<<<(Lq * HWq + 255) / 256, 256, 0, stream>>>(f, flow);
    k_m0<<<HWq / 256, 256, 0, stream>>>(h0, mA);

    float* bufs[2] = {mA, mB};
    for (int l = 0; l < Lq; l++) {
        float* min_ = bufs[l & 1];
        float* mout = bufs[(l + 1) & 1];
        k_step<<<Hq, 1024, 0, stream>>>(min_, mout, flow + (size_t)l * 2 * HWq,
                                        x + (size_t)l * Cq * HWq, listT, l,
                                        sw1, sb1, sw2, sb2,
                                        out + (size_t)l * Cq * HWq);
    }
}

// Round 13
// 177.462 us; speedup vs baseline: 1.2346x; 1.2346x over previous
//
#include <hip/hip_runtime.h>
#include <math.h>

constexpr int Lq = 8, Cq = 16, Hq = 240, Wq = 480, MIDq = 8, SEM = 4;
constexpr int HWq = Hq * Wq;

__device__ __forceinline__ float sigmoidf_(float v) { return 1.0f / (1.0f + expf(-v)); }

// conv1: x (L,16,H,W) -> silu -> f1 (L,8,H,W), 3x3 SAME zero-pad.
// R13: R5's exact load ORDER (ic-major, 3 rows) -> preserves the 29MB ideal
// FETCH; but hoist the 9 loads of each ic-group into registers before the
// 288 FMAs, and raise the VGPR cap (R5 got 28 VGPR -> 1-deep load chain).
// OOB rows: clamped address x validity-scale (branchless, exact zero-pad).
__global__ __launch_bounds__(128, 4) void k_conv1(const float* __restrict__ x,
                        const float* __restrict__ w1,
                        const float* __restrict__ b1, float* __restrict__ f1) {
    int b = blockIdx.x;
    int l = b & 7, y = b >> 3;
    int t = threadIdx.x;
    if (t >= 120) return;
    int xi = t * 4;
    float acc[MIDq][4];
#pragma unroll
    for (int m = 0; m < MIDq; m++) {
        float bv = b1[m];
#pragma unroll
        for (int o = 0; o < 4; o++) acc[m][o] = bv;
    }
    int yy0 = y > 0 ? y - 1 : 0;
    int yy2 = y < Hq - 1 ? y + 1 : Hq - 1;
    float v0 = y > 0 ? 1.f : 0.f;
    float v2 = y < Hq - 1 ? 1.f : 0.f;
    bool lok = xi > 0, rok = xi + 4 < Wq;
    const float* xb = x + (size_t)l * Cq * HWq;
#pragma unroll 1
    for (int ic = 0; ic < Cq; ic++) {
        const float* p0 = xb + (size_t)ic * HWq + yy0 * Wq;
        const float* p1 = xb + (size_t)ic * HWq + y * Wq;
        const float* p2 = xb + (size_t)ic * HWq + yy2 * Wq;
        float4 m0 = *(const float4*)(p0 + xi);
        float4 m1 = *(const float4*)(p1 + xi);
        float4 m2 = *(const float4*)(p2 + xi);
        float l0 = lok ? p0[xi - 1] : 0.f;
        float l1 = lok ? p1[xi - 1] : 0.f;
        float l2 = lok ? p2[xi - 1] : 0.f;
        float r0 = rok ? p0[xi + 4] : 0.f;
        float r1 = rok ? p1[xi + 4] : 0.f;
        float r2 = rok ? p2[xi + 4] : 0.f;
        float in0[6] = {l0 * v0, m0.x * v0, m0.y * v0, m0.z * v0, m0.w * v0, r0 * v0};
        float in1[6] = {l1, m1.x, m1.y, m1.z, m1.w, r1};
        float in2[6] = {l2 * v2, m2.x * v2, m2.y * v2, m2.z * v2, m2.w * v2, r2 * v2};
        const float* wic = w1 + ic * 9;
#pragma unroll
        for (int m = 0; m < MIDq; m++) {
            const float* wp = wic + (size_t)m * (Cq * 9);
            float w00 = wp[0], w01 = wp[1], w02 = wp[2];
            float w10 = wp[3], w11 = wp[4], w12 = wp[5];
            float w20 = wp[6], w21 = wp[7], w22 = wp[8];
#pragma unroll
            for (int o = 0; o < 4; o++) {
                float a = acc[m][o];
                a = fmaf(w00, in0[o], fmaf(w01, in0[o + 1], fmaf(w02, in0[o + 2], a)));
                a = fmaf(w10, in1[o], fmaf(w11, in1[o + 1], fmaf(w12, in1[o + 2], a)));
                a = fmaf(w20, in2[o], fmaf(w21, in2[o + 1], fmaf(w22, in2[o + 2], a)));
                acc[m][o] = a;
            }
        }
    }
    size_t rowoff = (size_t)y * Wq + xi;
#pragma unroll
    for (int m = 0; m < MIDq; m++) {
        float4 v;
        float a0 = acc[m][0], a1 = acc[m][1], a2 = acc[m][2], a3 = acc[m][3];
        v.x = a0 * sigmoidf_(a0);
        v.y = a1 * sigmoidf_(a1);
        v.z = a2 * sigmoidf_(a2);
        v.w = a3 * sigmoidf_(a3);
        *(float4*)(f1 + (size_t)(l * MIDq + m) * HWq + rowoff) = v;
    }
}

// conv2: f1 (L,8,H,W) -> f (L,2,H,W), 3x3 SAME zero-pad. Same treatment.
__global__ __launch_bounds__(128, 4) void k_conv2(const float* __restrict__ f1,
                        const float* __restrict__ w2,
                        const float* __restrict__ b2, float* __restrict__ f) {
    int b = blockIdx.x;
    int l = b & 7, y = b >> 3;
    int t = threadIdx.x;
    if (t >= 120) return;
    int xi = t * 4;
    float acc[2][4];
#pragma unroll
    for (int m = 0; m < 2; m++) {
        float bv = b2[m];
#pragma unroll
        for (int o = 0; o < 4; o++) acc[m][o] = bv;
    }
    int yy0 = y > 0 ? y - 1 : 0;
    int yy2 = y < Hq - 1 ? y + 1 : Hq - 1;
    float v0 = y > 0 ? 1.f : 0.f;
    float v2 = y < Hq - 1 ? 1.f : 0.f;
    bool lok = xi > 0, rok = xi + 4 < Wq;
    const float* fb = f1 + (size_t)l * MIDq * HWq;
#pragma unroll 1
    for (int ic = 0; ic < MIDq; ic++) {
        const float* p0 = fb + (size_t)ic * HWq + yy0 * Wq;
        const float* p1 = fb + (size_t)ic * HWq + y * Wq;
        const float* p2 = fb + (size_t)ic * HWq + yy2 * Wq;
        float4 m0 = *(const float4*)(p0 + xi);
        float4 m1 = *(const float4*)(p1 + xi);
        float4 m2 = *(const float4*)(p2 + xi);
        float l0 = lok ? p0[xi - 1] : 0.f;
        float l1 = lok ? p1[xi - 1] : 0.f;
        float l2 = lok ? p2[xi - 1] : 0.f;
        float r0 = rok ? p0[xi + 4] : 0.f;
        float r1 = rok ? p1[xi + 4] : 0.f;
        float r2 = rok ? p2[xi + 4] : 0.f;
        float in0[6] = {l0 * v0, m0.x * v0, m0.y * v0, m0.z * v0, m0.w * v0, r0 * v0};
        float in1[6] = {l1, m1.x, m1.y, m1.z, m1.w, r1};
        float in2[6] = {l2 * v2, m2.x * v2, m2.y * v2, m2.z * v2, m2.w * v2, r2 * v2};
        const float* wic = w2 + ic * 9;
#pragma unroll
        for (int m = 0; m < 2; m++) {
            const float* wp = wic + (size_t)m * (MIDq * 9);
            float w00 = wp[0], w01 = wp[1], w02 = wp[2];
            float w10 = wp[3], w11 = wp[4], w12 = wp[5];
            float w20 = wp[6], w21 = wp[7], w22 = wp[8];
#pragma unroll
            for (int o = 0; o < 4; o++) {
                float a = acc[m][o];
                a = fmaf(w00, in0[o], fmaf(w01, in0[o + 1], fmaf(w02, in0[o + 2], a)));
                a = fmaf(w10, in1[o], fmaf(w11, in1[o + 1], fmaf(w12, in1[o + 2], a)));
                a = fmaf(w20, in2[o], fmaf(w21, in2[o + 1], fmaf(w22, in2[o + 2], a)));
                acc[m][o] = a;
            }
        }
    }
    size_t rowoff = (size_t)y * Wq + xi;
#pragma unroll
    for (int m = 0; m < 2; m++) {
        float4 v = {acc[m][0], acc[m][1], acc[m][2], acc[m][3]};
        *(float4*)(f + (size_t)(l * 2 + m) * HWq + rowoff) = v;
    }
}

// sobel (wrap-x, edge-y) + metric + tanh -> flow (L,2,H,W) (R5 exact)
__global__ void k_flow(const float* __restrict__ f, float* __restrict__ flow) {
    int idx = blockIdx.x * blockDim.x + threadIdx.x;
    if (idx >= Lq * HWq) return;
    int l = idx / HWq, rem = idx % HWq, y = rem / Wq, x = rem % Wq;
    const float* phi = f + (size_t)(l * 2 + 0) * HWq;
    const float* psi = f + (size_t)(l * 2 + 1) * HWq;
    float ph[3][3], ps[3][3];
#pragma unroll
    for (int i = 0; i < 3; i++) {
        int yy = y + i - 1;
        yy = yy < 0 ? 0 : (yy >= Hq ? Hq - 1 : yy);
#pragma unroll
        for (int j = 0; j < 3; j++) {
            int xx = x + j - 1;
            xx = (xx + Wq) % Wq;
            ph[i][j] = phi[yy * Wq + xx];
            ps[i][j] = psi[yy * Wq + xx];
        }
    }
    float gxp = (ph[0][2] - ph[0][0]) + 2.f * (ph[1][2] - ph[1][0]) + (ph[2][2] - ph[2][0]);
    float gyp = (ph[2][0] + 2.f * ph[2][1] + ph[2][2]) - (ph[0][0] + 2.f * ph[0][1] + ph[0][2]);
    float gxs = (ps[0][2] - ps[0][0]) + 2.f * (ps[1][2] - ps[1][0]) + (ps[2][2] - ps[2][0]);
    float gys = (ps[2][0] + 2.f * ps[2][1] + ps[2][2]) - (ps[0][0] + 2.f * ps[0][1] + ps[0][2]);
    float latf = (float)(-M_PI * 0.5 + (double)y * (M_PI / (double)(Hq - 1)));
    float metric = (float)(1.0 / (cos((double)latf) + 1e-6));
    float u = gxp * metric - gys;
    float v = gyp + gxs * metric;
    flow[(size_t)(l * 2 + 0) * HWq + rem] = tanhf(u);
    flow[(size_t)(l * 2 + 1) * HWq + rem] = tanhf(v);
}

// one-time: m0[px][c] = mean_r h0[c][px][r]   (h0: (C,H,W,R) fp32, R=8)
__global__ void k_m0(const float* __restrict__ h0, float* __restrict__ m0) {
    int px = blockIdx.x * 256 + threadIdx.x;
    const float4* h4 = (const float4*)h0;
    float4* mp = (float4*)(m0 + (size_t)px * Cq);
#pragma unroll
    for (int cq = 0; cq < 4; cq++) {
        float vals[4];
#pragma unroll
        for (int cc = 0; cc < 4; cc++) {
            int c = cq * 4 + cc;
            float4 a = h4[(size_t)(c * HWq + px) * 2];
            float4 b = h4[(size_t)(c * HWq + px) * 2 + 1];
            vals[cc] = (a.x + a.y + a.z + a.w + b.x + b.y + b.z + b.w) * 0.125f;
        }
        float4 o = {vals[0], vals[1], vals[2], vals[3]};
        mp[cq] = o;
    }
}

// Fused scan step (R11 form: 2 barriers, SE recomputed in registers).
__global__ __launch_bounds__(1024) void k_step(const float* __restrict__ min_,
                       float* __restrict__ mout, const float* __restrict__ flow_l,
                       const float* __restrict__ xl, const float* __restrict__ listT,
                       int l,
                       const float* __restrict__ sw1, const float* __restrict__ sb1,
                       const float* __restrict__ sw2, const float* __restrict__ sb2,
                       float* __restrict__ out_l) {
    constexpr int STR = 17;                     // LDS row stride (coprime 32)
    __shared__ float sm[Wq * STR];
    __shared__ float csum[Cq];

    int y = blockIdx.x;
    int t = threadIdx.x;
    int wave = t >> 6, lane = t & 63;
    bool act = t < 2 * Wq;
    int px = act ? (t >> 1) : (Wq - 1);
    int half = t & 1;
    int c0 = half * 8;

    float dt = listT[l];
    float mn[8];
    {
        float u = flow_l[y * Wq + px];
        float v = flow_l[HWq + y * Wq + px];
        float gx = (px * (2.0f / (Wq - 1)) - 1.0f) - u * dt;
        float gy = (y * (2.0f / (Hq - 1)) - 1.0f) - v * dt;
        float xp = fminf(fmaxf((gx + 1.0f) * (Wq * 0.5f) - 0.5f, 0.0f), (float)(Wq - 1));
        float yp = fminf(fmaxf((gy + 1.0f) * (Hq * 0.5f) - 0.5f, 0.0f), (float)(Hq - 1));
        float x0f = floorf(xp), y0f = floorf(yp);
        float wx = xp - x0f, wy = yp - y0f;
        int x0 = (int)x0f, y0 = (int)y0f;
        int x1 = min(x0 + 1, Wq - 1), y1 = min(y0 + 1, Hq - 1);
        const float4* m4 = (const float4*)min_;
        size_t b00 = (size_t)(y0 * Wq + x0) * 4 + (half * 2);
        size_t b01 = (size_t)(y0 * Wq + x1) * 4 + (half * 2);
        size_t b10 = (size_t)(y1 * Wq + x0) * 4 + (half * 2);
        size_t b11 = (size_t)(y1 * Wq + x1) * 4 + (half * 2);
        float4 A0 = m4[b00], A1 = m4[b00 + 1];
        float4 B0 = m4[b01], B1 = m4[b01 + 1];
        float4 C0 = m4[b10], C1 = m4[b10 + 1];
        float4 D0 = m4[b11], D1 = m4[b11 + 1];
        float w00 = (1.f - wx) * (1.f - wy), w01 = wx * (1.f - wy);
        float w10 = (1.f - wx) * wy, w11 = wx * wy;
        const float* xb = xl + y * Wq + px;
        float xv[8];
#pragma unroll
        for (int j = 0; j < 8; j++) xv[j] = xb[(size_t)(c0 + j) * HWq];
        mn[0] = w00 * A0.x + w01 * B0.x + w10 * C0.x + w11 * D0.x + xv[0];
        mn[1] = w00 * A0.y + w01 * B0.y + w10 * C0.y + w11 * D0.y + xv[1];
        mn[2] = w00 * A0.z + w01 * B0.z + w10 * C0.z + w11 * D0.z + xv[2];
        mn[3] = w00 * A0.w + w01 * B0.w + w10 * C0.w + w11 * D0.w + xv[3];
        mn[4] = w00 * A1.x + w01 * B1.x + w10 * C1.x + w11 * D1.x + xv[4];
        mn[5] = w00 * A1.y + w01 * B1.y + w10 * C1.y + w11 * D1.y + xv[5];
        mn[6] = w00 * A1.z + w01 * B1.z + w10 * C1.z + w11 * D1.z + xv[6];
        mn[7] = w00 * A1.w + w01 * B1.w + w10 * C1.w + w11 * D1.w + xv[7];
    }
    if (act) {
        float4* mo = (float4*)(mout + (size_t)(y * Wq + px) * Cq + c0);
        float4 o0 = {mn[0], mn[1], mn[2], mn[3]};
        float4 o1 = {mn[4], mn[5], mn[6], mn[7]};
        mo[0] = o0;
        mo[1] = o1;
#pragma unroll
        for (int j = 0; j < 8; j++) sm[px * STR + c0 + j] = mn[j];
    }
    __syncthreads();
    {
        float s = 0.f;
#pragma unroll
        for (int k = 0; k < 8; k++) {
            int p = k * 64 + lane;
            if (p < Wq) s += sm[p * STR + wave];
        }
#pragma unroll
        for (int off = 32; off > 0; off >>= 1) s += __shfl_down(s, off, 64);
        if (lane == 0) csum[wave] = s;
    }
    __syncthreads();
    if (act) {
        float ym[Cq];
#pragma unroll
        for (int i = 0; i < Cq; i++) ym[i] = csum[i] * (1.0f / Wq);
        float z[SEM];
#pragma unroll
        for (int mm = 0; mm < SEM; mm++) {
            float a = sb1[mm];
#pragma unroll
            for (int i = 0; i < Cq; i++) a = fmaf(sw1[mm * Cq + i], ym[i], a);
            z[mm] = a * sigmoidf_(a);
        }
        float* ob = out_l + y * Wq + px;
#pragma unroll
        for (int j = 0; j < 8; j++) {
            float a = sb2[c0 + j];
#pragma unroll
            for (int mm = 0; mm < SEM; mm++) a = fmaf(sw2[(c0 + j) * SEM + mm], z[mm], a);
            ob[(size_t)(c0 + j) * HWq] = mn[j] * sigmoidf_(a);
        }
    }
}

extern "C" void kernel_launch(void* const* d_in, const int* in_sizes, int n_in,
                              void* d_out, int out_size, void* d_ws, size_t ws_size,
                              hipStream_t stream) {
    const float* x = (const float*)d_in[0];
    const float* h0 = (const float*)d_in[1];
    const float* listT = (const float*)d_in[2];
    const float* hw1 = (const float*)d_in[3];
    const float* hb1 = (const float*)d_in[4];
    const float* hw2 = (const float*)d_in[5];
    const float* hb2 = (const float*)d_in[6];
    const float* sw1 = (const float*)d_in[7];
    const float* sb1 = (const float*)d_in[8];
    const float* sw2 = (const float*)d_in[9];
    const float* sb2 = (const float*)d_in[10];
    float* out = (float*)d_out;
    char* ws = (char*)d_ws;

    size_t off = 0;
    float* flow = (float*)(ws + off); off += sizeof(float) * (size_t)Lq * 2 * HWq;
    float* f    = (float*)(ws + off); off += sizeof(float) * (size_t)Lq * 2 * HWq;
    float* f1   = (float*)(ws + off); off += sizeof(float) * (size_t)Lq * MIDq * HWq;
    float* mA   = (float*)(ws + off); off += sizeof(float) * (size_t)HWq * Cq;
    float* mB   = (float*)(ws + off); off += sizeof(float) * (size_t)HWq * Cq;

    k_conv1<<<Lq * Hq, 128, 0, stream>>>(x, hw1, hb1, f1);
    k_conv2<<<Lq * Hq, 128, 0, stream>>>(f1, hw2, hb2, f);
    k_flow<<<(Lq * HWq + 255) / 256, 256, 0, stream>>>(f, flow);
    k_m0<<<HWq / 256, 256, 0, stream>>>(h0, mA);

    float* bufs[2] = {mA, mB};
    for (int l = 0; l < Lq; l++) {
        float* min_ = bufs[l & 1];
        float* mout = bufs[(l + 1) & 1];
        k_step<<<Hq, 1024, 0, stream>>>(min_, mout, flow + (size_t)l * 2 * HWq,
                                        x + (size_t)l * Cq * HWq, listT, l,
                                        sw1, sb1, sw2, sb2,
                                        out + (size_t)l * Cq * HWq);
    }
}